// Round 3
// baseline (279.548 us; speedup 1.0000x reference)
//
#include <hip/hip_runtime.h>
#include <hip/hip_fp16.h>

// Problem constants
#define W 512
#define H 512
#define HW (512*512)          // 262144 = 2^18
#define NCH 3
#define MBINS 4096            // median histogram bins over [0,1)
#define PBINS 1024            // percentile histogram bins, value = (bin-512)/256
#define MEDK ((HW-1)/2)       // 131071, 0-indexed lower-median rank
#define KW 23                 // filter width
#define KR 11                 // radius

// conv tile geometry
#define TR 32                 // output rows per block
#define TC 128                // output cols per block
#define SR (TR + 2*KR)        // 54 staged rows
#define SC (TC + 2*KR)        // 150 staged cols
#define FSTR 161              // fillbuf stride (161%32==1 -> conflict-free h reads)
#define HSTR 131              // hbuf stride (odd -> spread banks)
#define HBLK 16               // k_hist blocks per group
#define CBLK 64               // k_conv blocks per group (16 rowbands x 4 colbands)

// ---------------- s1d = row sums of 2D kernel (separable factor) ----------------
__global__ void k_prep(const float* __restrict__ kern, float* __restrict__ s1d) {
    int i = threadIdx.x;
    if (i < KW) {
        float s = 0.f;
        for (int j = 0; j < KW; ++j) s += kern[i*KW + j];
        s1d[i] = s;
    }
}

// ------- median histogram: bin = trunc(x*4096); PRIVATE per-block store (no atomics) -------
__global__ __launch_bounds__(256) void k_hist(const float* __restrict__ x,
                                              unsigned int* __restrict__ hist) {
    __shared__ unsigned int h[MBINS];
    int g = blockIdx.x >> 4;        // 16 blocks per group
    int chunk = blockIdx.x & 15;    // 16384 elems per block
    for (int i = threadIdx.x; i < MBINS; i += 256) h[i] = 0u;
    __syncthreads();
    const float4* xp = (const float4*)(x + (size_t)g*HW + (size_t)chunk*16384);
    #pragma unroll
    for (int it = 0; it < 16; ++it) {
        float4 v = xp[it*256 + threadIdx.x];
        int b0 = min(MBINS-1, (int)(v.x * (float)MBINS));
        int b1 = min(MBINS-1, (int)(v.y * (float)MBINS));
        int b2 = min(MBINS-1, (int)(v.z * (float)MBINS));
        int b3 = min(MBINS-1, (int)(v.w * (float)MBINS));
        atomicAdd(&h[b0], 1u); atomicAdd(&h[b1], 1u);
        atomicAdd(&h[b2], 1u); atomicAdd(&h[b3], 1u);
    }
    __syncthreads();
    unsigned int* gh = hist + (size_t)blockIdx.x*MBINS;   // private slice
    for (int i = threadIdx.x; i < MBINS; i += 256) gh[i] = h[i];
}

// ------ median select: sum 16 private hists, parallel scan + rank lookup ------
__global__ __launch_bounds__(256) void k_medsel(const unsigned int* __restrict__ hist,
                                                float* __restrict__ med) {
    __shared__ unsigned int scan[256];
    const int g = blockIdx.x;
    const int tid = threadIdx.x;
    unsigned int local[16];
    #pragma unroll
    for (int i = 0; i < 16; ++i) local[i] = 0u;
    for (int c = 0; c < HBLK; ++c) {
        const uint4* p = (const uint4*)(hist + ((size_t)(g*HBLK + c))*MBINS + tid*16);
        #pragma unroll
        for (int q = 0; q < 4; ++q) {
            uint4 v = p[q];
            local[q*4+0] += v.x; local[q*4+1] += v.y;
            local[q*4+2] += v.z; local[q*4+3] += v.w;
        }
    }
    unsigned int s = 0;
    #pragma unroll
    for (int i = 0; i < 16; ++i) s += local[i];
    scan[tid] = s;
    __syncthreads();
    #pragma unroll
    for (int off = 1; off < 256; off <<= 1) {
        unsigned int t = (tid >= off) ? scan[tid - off] : 0u;
        __syncthreads();
        scan[tid] += t;
        __syncthreads();
    }
    unsigned int p = scan[tid] - s;   // exclusive prefix before this thread's 16 bins
    if (p <= (unsigned)MEDK && (unsigned)MEDK < p + s) {   // unique owner thread
        unsigned int c = p;
        #pragma unroll
        for (int i = 0; i < 16; ++i) {
            if (c + local[i] > (unsigned)MEDK) {
                int bin = tid*16 + i;
                float frac = ((float)(MEDK - c) + 0.5f) / (float)local[i];
                med[g] = ((float)bin + frac) * (1.0f/(float)MBINS) + 0.2f;
                break;
            }
            c += local[i];
        }
    }
}

// ---- fused separable conv: 3-phase tile (stage -> h-pass -> v-pass), 3 barriers ----
__global__ __launch_bounds__(512) void k_conv(const float* __restrict__ x,
                                              const float* __restrict__ mask,
                                              const float* __restrict__ med,
                                              const float* __restrict__ s1d,
                                              __half* __restrict__ res,
                                              unsigned int* __restrict__ phist) {
    __shared__ float fill[SR*FSTR];      // 34776 B
    __shared__ float hbuf[SR*HSTR];      // 28296 B
    __shared__ float sk[KW];
    __shared__ unsigned int h[PBINS];    // 4096 B
    const int b   = blockIdx.x;
    const int g   = b >> 6;              // 48 groups
    const int sub = b & 63;
    const int rb  = sub >> 2;            // 16 row bands
    const int cb  = sub & 3;             // 4 col bands
    const int r0  = rb*TR, c0 = cb*TC;
    const int n   = g / NCH;
    const int tid = threadIdx.x;
    for (int i = tid; i < PBINS; i += 512) h[i] = 0u;
    if (tid < KW) sk[tid] = s1d[tid];
    const float medv = med[g];
    const float* xg = x    + (size_t)g*HW;
    const float* mg = mask + (size_t)n*HW;

    // ---- stage: filled = mask*x + (1-mask)*med, zero outside image ----
    for (int idx = tid; idx < SR*FSTR; idx += 512) {
        int row = idx / FSTR;            // constant division -> magic mul
        int col = idx - row*FSTR;
        if (col < SC) {
            int gr = r0 + row - KR;
            int gc = c0 + col - KR;
            float v = 0.f;
            if (gr >= 0 && gr < H && gc >= 0 && gc < W) {
                float mv = mg[gr*W + gc];
                v = mv*xg[gr*W + gc] + (1.f - mv)*medv;
            }
            fill[idx] = v;
        }
    }
    __syncthreads();

    // ---- h-pass: 54 rows x 128 cols; thread = (row, 8-col group), register slide ----
    {
        int row = tid & 63;              // 54 active
        int cg0 = tid >> 6;              // 0..7
        if (row < SR) {
            #pragma unroll
            for (int half = 0; half < 2; ++half) {
                int cg = cg0 + half*8;
                int base = row*FSTR + cg*8;
                float wv[KW+7];          // 30, all static indices
                #pragma unroll
                for (int j = 0; j < KW+7; ++j) wv[j] = fill[base + j];
                #pragma unroll
                for (int k = 0; k < 8; ++k) {
                    float acc = 0.f;
                    #pragma unroll
                    for (int j = 0; j < KW; ++j) acc += sk[j]*wv[k+j];
                    hbuf[row*HSTR + cg*8 + k] = acc;
                }
            }
        }
    }
    __syncthreads();

    // ---- v-pass: thread = (col, 8-row group); res + percentile binning ----
    {
        int col = tid & 127;
        int rg  = tid >> 7;              // 0..3
        int lr0 = rg*8;
        float wv[KW+7];                  // 30 h-values down the column
        #pragma unroll
        for (int t = 0; t < KW+7; ++t) wv[t] = hbuf[(lr0 + t)*HSTR + col];
        __half* rout = res + (size_t)g*HW;
        #pragma unroll
        for (int o = 0; o < 8; ++o) {
            float blur = 0.f;
            #pragma unroll
            for (int j = 0; j < KW; ++j) blur += sk[j]*wv[o+j];
            float fv = fill[(lr0 + o + KR)*FSTR + col + KR];
            float rv = fv - blur;
            int r = r0 + lr0 + o;
            rout[r*W + c0 + col] = __float2half(rv);
            int bin = (int)truncf(rv*256.f) + 512;
            bin = min(PBINS-1, max(0, bin));
            atomicAdd(&h[bin], 1u);
        }
    }
    __syncthreads();
    unsigned int* gh = phist + (size_t)b*PBINS;    // private slice, plain stores
    for (int i = tid; i < PBINS; i += 512) gh[i] = h[i];
}

// ------ percentile select: sum 64 private hists, parallel scan + rank lookup ------
__global__ __launch_bounds__(256) void k_pct(const unsigned int* __restrict__ phist,
                                             float* __restrict__ lohi) {
    __shared__ unsigned int scan[256];
    __shared__ float vsh[4];
    const int g = blockIdx.x;
    const int tid = threadIdx.x;
    unsigned int local[4];
    #pragma unroll
    for (int i = 0; i < 4; ++i) local[i] = 0u;
    for (int c = 0; c < CBLK; ++c) {
        uint4 v = *(const uint4*)(phist + ((size_t)(g*CBLK + c))*PBINS + tid*4);
        local[0] += v.x; local[1] += v.y; local[2] += v.z; local[3] += v.w;
    }
    unsigned int s = local[0] + local[1] + local[2] + local[3];
    scan[tid] = s;
    __syncthreads();
    #pragma unroll
    for (int off = 1; off < 256; off <<= 1) {
        unsigned int t = (tid >= off) ? scan[tid - off] : 0u;
        __syncthreads();
        scan[tid] += t;
        __syncthreads();
    }
    unsigned int p = scan[tid] - s;   // exclusive prefix
    const double dl = (3.0/100.0)*(double)(HW-1);    // 7864.29
    const double dh = (97.0/100.0)*(double)(HW-1);   // 254278.71
    const long il = (long)dl, ih = (long)dh;
    const long ranks[4] = {il, il+1, ih, ih+1};
    #pragma unroll
    for (int ri = 0; ri < 4; ++ri) {
        long r = ranks[ri];
        if ((long)p <= r && r < (long)(p + s)) {     // owner thread for this rank
            unsigned int c = p;
            #pragma unroll
            for (int i = 0; i < 4; ++i) {
                if ((long)(c + local[i]) > r) {
                    vsh[ri] = (float)(tid*4 + i - 512) * (1.0f/256.0f);
                    break;
                }
                c += local[i];
            }
        }
    }
    __syncthreads();
    if (tid == 0) {
        double fl = dl - (double)il, fh = dh - (double)ih;
        double lo = (double)vsh[0] + fl*((double)vsh[1] - (double)vsh[0]);
        double hi = (double)vsh[2] + fh*((double)vsh[3] - (double)vsh[2]);
        lohi[2*g]   = (float)lo;
        lohi[2*g+1] = (float)hi;
    }
}

// ---------- final: out = (res_f16 - lo)/(hi - lo) * mask; 8 px/thread ----------
__global__ __launch_bounds__(256) void k_final(const __half* __restrict__ res,
                                               const float* __restrict__ mask,
                                               const float* __restrict__ lohi,
                                               float* __restrict__ out) {
    size_t idx8 = (size_t)blockIdx.x*256 + threadIdx.x;   // 1,572,864 total
    size_t base = idx8*8;
    int g = (int)(base >> 18);
    int n = g / NCH;
    float lo = lohi[2*g], hi = lohi[2*g+1];
    float inv = 1.0f/(hi - lo);
    uint4 rbits = *(const uint4*)(res + base);            // 8 halves
    const __half* rh = (const __half*)&rbits;
    size_t moff = ((size_t)n << 18) + (base & (size_t)(HW-1));
    float4 m0 = *(const float4*)(mask + moff);
    float4 m1 = *(const float4*)(mask + moff + 4);
    float4 o0, o1;
    o0.x = (__half2float(rh[0]) - lo)*inv*m0.x;
    o0.y = (__half2float(rh[1]) - lo)*inv*m0.y;
    o0.z = (__half2float(rh[2]) - lo)*inv*m0.z;
    o0.w = (__half2float(rh[3]) - lo)*inv*m0.w;
    o1.x = (__half2float(rh[4]) - lo)*inv*m1.x;
    o1.y = (__half2float(rh[5]) - lo)*inv*m1.y;
    o1.z = (__half2float(rh[6]) - lo)*inv*m1.z;
    o1.w = (__half2float(rh[7]) - lo)*inv*m1.w;
    *(float4*)(out + base)     = o0;
    *(float4*)(out + base + 4) = o1;
}

extern "C" void kernel_launch(void* const* d_in, const int* in_sizes, int n_in,
                              void* d_out, int out_size, void* d_ws, size_t ws_size,
                              hipStream_t stream) {
    const float* x    = (const float*)d_in[0];   // [16,3,512,512] f32
    const float* mask = (const float*)d_in[1];   // [16,1,512,512] f32
    const float* kern = (const float*)d_in[2];   // [23,23] f32
    float* out = (float*)d_out;

    char* ws = (char*)d_ws;
    // Workspace layout (~50.33 MB, all write-before-read -> no memset needed):
    //   [0, 12582912)            phist : 3072 private 1024-bin u32 hists
    //   [12582912, 25165824)     mhist : 768 private 4096-bin u32 hists
    //   [25165824, 50331648)     res16 : 12.58M f16 residual
    //   [50331648, +192)         med   : 48 f32
    //   [50331904, +92)          s1d   : 23 f32
    //   [50332160, +384)         lohi  : 96 f32
    unsigned int* phist = (unsigned int*)ws;
    unsigned int* mhist = (unsigned int*)(ws + 12582912);
    __half*       res16 = (__half*)      (ws + 25165824);
    float* med  = (float*)(ws + 50331648);
    float* s1d  = (float*)(ws + 50331904);
    float* lohi = (float*)(ws + 50332160);

    k_prep  <<<1,    32,  0, stream>>>(kern, s1d);
    k_hist  <<<768,  256, 0, stream>>>(x, mhist);
    k_medsel<<<48,   256, 0, stream>>>(mhist, med);
    k_conv  <<<3072, 512, 0, stream>>>(x, mask, med, s1d, res16, phist);
    k_pct   <<<48,   256, 0, stream>>>(phist, lohi);
    k_final <<<6144, 256, 0, stream>>>(res16, mask, lohi, out);
}

// Round 4
// 268.551 us; speedup vs baseline: 1.0410x; 1.0410x over previous
//
#include <hip/hip_runtime.h>
#include <hip/hip_fp16.h>

// Problem constants
#define W 512
#define H 512
#define HW (512*512)          // 262144 = 2^18
#define NCH 3
#define MBINS 4096            // median histogram bins over [0,1)
#define PBINS 1024            // percentile histogram bins, value = (bin-512)/256
#define MEDK ((HW-1)/2)       // 131071, 0-indexed lower-median rank
#define KW 23                 // filter width
#define KR 11                 // radius

// conv tile geometry
#define TR 32                 // output rows per block
#define TC 128                // output cols per block
#define SR (TR + 2*KR)        // 54 staged rows
#define SC (TC + 2*KR)        // 150 staged cols
#define FSTR 151              // fill stride in f32 (151%32=23, coprime -> <=2-way banks)
#define HSTR2 65              // hbuf stride in half2 pairs (65%32=1 -> spread)
#define HBLK 16               // k_hist blocks per group
#define CBLK 64               // k_conv blocks per group (16 rowbands x 4 colbands)
#define SENT 0x7C00u          // f16 +inf sentinel: "mask==0 here"

typedef float f32x2 __attribute__((ext_vector_type(2)));

// ------- median histogram: bin = trunc(x*4096); PRIVATE per-block store (no atomics) -------
__global__ __launch_bounds__(256) void k_hist(const float* __restrict__ x,
                                              unsigned int* __restrict__ hist) {
    __shared__ unsigned int h[MBINS];
    int g = blockIdx.x >> 4;        // 16 blocks per group
    int chunk = blockIdx.x & 15;    // 16384 elems per block
    for (int i = threadIdx.x; i < MBINS; i += 256) h[i] = 0u;
    __syncthreads();
    const float4* xp = (const float4*)(x + (size_t)g*HW + (size_t)chunk*16384);
    #pragma unroll
    for (int it = 0; it < 16; ++it) {
        float4 v = xp[it*256 + threadIdx.x];
        int b0 = min(MBINS-1, (int)(v.x * (float)MBINS));
        int b1 = min(MBINS-1, (int)(v.y * (float)MBINS));
        int b2 = min(MBINS-1, (int)(v.z * (float)MBINS));
        int b3 = min(MBINS-1, (int)(v.w * (float)MBINS));
        atomicAdd(&h[b0], 1u); atomicAdd(&h[b1], 1u);
        atomicAdd(&h[b2], 1u); atomicAdd(&h[b3], 1u);
    }
    __syncthreads();
    unsigned int* gh = hist + (size_t)blockIdx.x*MBINS;   // private slice
    for (int i = threadIdx.x; i < MBINS; i += 256) gh[i] = h[i];
}

// ------ median select (+ k_prep merged into block 0): sum 16 private hists, scan, rank ------
__global__ __launch_bounds__(256) void k_medsel(const unsigned int* __restrict__ hist,
                                                const float* __restrict__ kern,
                                                float* __restrict__ s1d,
                                                float* __restrict__ med) {
    __shared__ unsigned int scan[256];
    const int g = blockIdx.x;
    const int tid = threadIdx.x;
    if (g == 0 && tid < KW) {       // separable factor: row sums of 2D kernel
        float s = 0.f;
        for (int j = 0; j < KW; ++j) s += kern[tid*KW + j];
        s1d[tid] = s;
    }
    unsigned int local[16];
    #pragma unroll
    for (int i = 0; i < 16; ++i) local[i] = 0u;
    for (int c = 0; c < HBLK; ++c) {
        const uint4* p = (const uint4*)(hist + ((size_t)(g*HBLK + c))*MBINS + tid*16);
        #pragma unroll
        for (int q = 0; q < 4; ++q) {
            uint4 v = p[q];
            local[q*4+0] += v.x; local[q*4+1] += v.y;
            local[q*4+2] += v.z; local[q*4+3] += v.w;
        }
    }
    unsigned int s = 0;
    #pragma unroll
    for (int i = 0; i < 16; ++i) s += local[i];
    scan[tid] = s;
    __syncthreads();
    #pragma unroll
    for (int off = 1; off < 256; off <<= 1) {
        unsigned int t = (tid >= off) ? scan[tid - off] : 0u;
        __syncthreads();
        scan[tid] += t;
        __syncthreads();
    }
    unsigned int p = scan[tid] - s;   // exclusive prefix before this thread's 16 bins
    if (p <= (unsigned)MEDK && (unsigned)MEDK < p + s) {   // unique owner thread
        unsigned int c = p;
        #pragma unroll
        for (int i = 0; i < 16; ++i) {
            if (c + local[i] > (unsigned)MEDK) {
                int bin = tid*16 + i;
                float frac = ((float)(MEDK - c) + 0.5f) / (float)local[i];
                med[g] = ((float)bin + frac) * (1.0f/(float)MBINS) + 0.2f;
                break;
            }
            c += local[i];
        }
    }
}

// ---- fused separable conv: 3-phase tile (stage -> h-pass -> v-pass), 3 barriers ----
// LDS 50.8 KB -> 3 blocks/CU (24 waves). hbuf in f16. Inner loops in f32x2 to
// encourage v_pk_fma_f32. res16 carries an inf sentinel where mask==0.
__global__ __launch_bounds__(512) void k_conv(const float* __restrict__ x,
                                              const float* __restrict__ mask,
                                              const float* __restrict__ med,
                                              const float* __restrict__ s1d,
                                              unsigned short* __restrict__ res,
                                              unsigned int* __restrict__ phist) {
    __shared__ float fill[SR*FSTR];      // 32616 B
    __shared__ __half2 hbuf2[SR*HSTR2]; // 14040 B
    __shared__ float sk[KW];
    __shared__ unsigned int h[PBINS];    // 4096 B
    const int b   = blockIdx.x;
    const int g   = b >> 6;              // 48 groups
    const int sub = b & 63;
    const int rb  = sub >> 2;            // 16 row bands
    const int cb  = sub & 3;             // 4 col bands
    const int r0  = rb*TR, c0 = cb*TC;
    const int n   = g / NCH;
    const int tid = threadIdx.x;
    for (int i = tid; i < PBINS; i += 512) h[i] = 0u;
    if (tid < KW) sk[tid] = s1d[tid];
    const float medv = med[g];
    const float* xg = x    + (size_t)g*HW;
    const float* mg = mask + (size_t)n*HW;

    // ---- stage: filled = mask*x + (1-mask)*med, zero outside image ----
    for (int idx = tid; idx < SR*FSTR; idx += 512) {
        int row = idx / FSTR;            // constant division -> magic mul
        int col = idx - row*FSTR;
        if (col < SC) {
            int gr = r0 + row - KR;
            int gc = c0 + col - KR;
            float v = 0.f;
            if (gr >= 0 && gr < H && gc >= 0 && gc < W) {
                float mv = mg[gr*W + gc];
                v = mv*xg[gr*W + gc] + (1.f - mv)*medv;
            }
            fill[idx] = v;
        }
    }
    __syncthreads();

    // ---- h-pass: thread = (row, col-group of 8); register window, f32x2 MACs ----
    {
        int row = tid & 63;              // 54 active
        int cg0 = tid >> 6;              // 0..7
        if (row < SR) {
            #pragma unroll
            for (int half = 0; half < 2; ++half) {
                int cg = cg0 + half*8;
                int base = row*FSTR + cg*8;
                float wv[KW+7];          // 30, all static indices
                #pragma unroll
                for (int j = 0; j < KW+7; ++j) wv[j] = fill[base + j];
                __half2* hrow = hbuf2 + row*HSTR2 + cg*4;
                #pragma unroll
                for (int k = 0; k < 8; k += 2) {
                    f32x2 acc = {0.f, 0.f};
                    #pragma unroll
                    for (int j = 0; j < KW; ++j) {
                        f32x2 pair = {wv[k+j], wv[k+1+j]};
                        acc += sk[j] * pair;
                    }
                    hrow[k>>1] = __floats2half2_rn(acc.x, acc.y);
                }
            }
        }
    }
    __syncthreads();

    // ---- v-pass: thread = (col, 8-row group); res + sentinel + percentile binning ----
    {
        int col = tid & 127;
        int rg  = tid >> 7;              // 0..3
        int lr0 = rg*8;
        const __half* hb = (const __half*)hbuf2;   // row stride 130 halves
        float wv[KW+7];                  // 30 h-values down the column
        #pragma unroll
        for (int t = 0; t < KW+7; ++t) wv[t] = __half2float(hb[(lr0 + t)*(2*HSTR2) + col]);
        unsigned short* rout = res + (size_t)g*HW;
        #pragma unroll
        for (int o = 0; o < 8; o += 2) {
            f32x2 acc = {0.f, 0.f};
            #pragma unroll
            for (int j = 0; j < KW; ++j) {
                f32x2 pair = {wv[o+j], wv[o+1+j]};
                acc += sk[j] * pair;
            }
            #pragma unroll
            for (int e = 0; e < 2; ++e) {
                int lr = lr0 + o + e;
                float fv = fill[(lr + KR)*FSTR + col + KR];
                float rv = fv - acc[e];
                int r = r0 + lr;
                float mv = mg[r*W + c0 + col];
                __half hv = __float2half(rv);
                rout[r*W + c0 + col] =
                    (mv != 0.f) ? __half_as_ushort(hv) : (unsigned short)SENT;
                int bin = (int)truncf(rv*256.f) + 512;
                bin = min(PBINS-1, max(0, bin));
                atomicAdd(&h[bin], 1u);
            }
        }
    }
    __syncthreads();
    unsigned int* gh = phist + (size_t)b*PBINS;    // private slice, plain stores
    for (int i = tid; i < PBINS; i += 512) gh[i] = h[i];
}

// ------ percentile select: sum 64 private hists, parallel scan + rank lookup ------
__global__ __launch_bounds__(256) void k_pct(const unsigned int* __restrict__ phist,
                                             float* __restrict__ lohi) {
    __shared__ unsigned int scan[256];
    __shared__ float vsh[4];
    const int g = blockIdx.x;
    const int tid = threadIdx.x;
    unsigned int local[4];
    #pragma unroll
    for (int i = 0; i < 4; ++i) local[i] = 0u;
    for (int c = 0; c < CBLK; ++c) {
        uint4 v = *(const uint4*)(phist + ((size_t)(g*CBLK + c))*PBINS + tid*4);
        local[0] += v.x; local[1] += v.y; local[2] += v.z; local[3] += v.w;
    }
    unsigned int s = local[0] + local[1] + local[2] + local[3];
    scan[tid] = s;
    __syncthreads();
    #pragma unroll
    for (int off = 1; off < 256; off <<= 1) {
        unsigned int t = (tid >= off) ? scan[tid - off] : 0u;
        __syncthreads();
        scan[tid] += t;
        __syncthreads();
    }
    unsigned int p = scan[tid] - s;   // exclusive prefix
    const double dl = (3.0/100.0)*(double)(HW-1);    // 7864.29
    const double dh = (97.0/100.0)*(double)(HW-1);   // 254278.71
    const long il = (long)dl, ih = (long)dh;
    const long ranks[4] = {il, il+1, ih, ih+1};
    #pragma unroll
    for (int ri = 0; ri < 4; ++ri) {
        long r = ranks[ri];
        if ((long)p <= r && r < (long)(p + s)) {     // owner thread for this rank
            unsigned int c = p;
            #pragma unroll
            for (int i = 0; i < 4; ++i) {
                if ((long)(c + local[i]) > r) {
                    vsh[ri] = (float)(tid*4 + i - 512) * (1.0f/256.0f);
                    break;
                }
                c += local[i];
            }
        }
    }
    __syncthreads();
    if (tid == 0) {
        double fl = dl - (double)il, fh = dh - (double)ih;
        double lo = (double)vsh[0] + fl*((double)vsh[1] - (double)vsh[0]);
        double hi = (double)vsh[2] + fh*((double)vsh[3] - (double)vsh[2]);
        lohi[2*g]   = (float)lo;
        lohi[2*g+1] = (float)hi;
    }
}

// ---- final: out = sentinel ? 0 : (res_f16 - lo)/(hi - lo); no mask read (75 MB total) ----
__global__ __launch_bounds__(256) void k_final(const unsigned short* __restrict__ res,
                                               const float* __restrict__ lohi,
                                               float* __restrict__ out) {
    size_t idx8 = (size_t)blockIdx.x*256 + threadIdx.x;   // 1,572,864 total
    size_t base = idx8*8;
    int g = (int)(base >> 18);
    float lo = lohi[2*g], hi = lohi[2*g+1];
    float inv = 1.0f/(hi - lo);
    uint4 rbits = *(const uint4*)(res + base);            // 8 ushorts
    const unsigned short* u = (const unsigned short*)&rbits;
    float4 o0, o1;
    float* po0 = (float*)&o0;
    float* po1 = (float*)&o1;
    #pragma unroll
    for (int e = 0; e < 4; ++e)
        po0[e] = (u[e] == (unsigned short)SENT)
                   ? 0.f : (__half2float(__ushort_as_half(u[e])) - lo)*inv;
    #pragma unroll
    for (int e = 0; e < 4; ++e)
        po1[e] = (u[4+e] == (unsigned short)SENT)
                   ? 0.f : (__half2float(__ushort_as_half(u[4+e])) - lo)*inv;
    *(float4*)(out + base)     = o0;
    *(float4*)(out + base + 4) = o1;
}

extern "C" void kernel_launch(void* const* d_in, const int* in_sizes, int n_in,
                              void* d_out, int out_size, void* d_ws, size_t ws_size,
                              hipStream_t stream) {
    const float* x    = (const float*)d_in[0];   // [16,3,512,512] f32
    const float* mask = (const float*)d_in[1];   // [16,1,512,512] f32
    const float* kern = (const float*)d_in[2];   // [23,23] f32
    float* out = (float*)d_out;

    char* ws = (char*)d_ws;
    // Workspace layout (~50.4 MB, all write-before-read -> no memset needed):
    //   [0, 12582912)            phist : 3072 private 1024-bin u32 hists
    //   [12582912, 25165824)     mhist : 768 private 4096-bin u32 hists
    //   [25165824, 50331648)     res16 : 12.58M ushort (f16 residual / inf sentinel)
    //   [50331648, +192)         med   : 48 f32
    //   [50331904, +92)          s1d   : 23 f32
    //   [50332160, +384)         lohi  : 96 f32
    unsigned int*   phist = (unsigned int*)ws;
    unsigned int*   mhist = (unsigned int*)(ws + 12582912);
    unsigned short* res16 = (unsigned short*)(ws + 25165824);
    float* med  = (float*)(ws + 50331648);
    float* s1d  = (float*)(ws + 50331904);
    float* lohi = (float*)(ws + 50332160);

    k_hist  <<<768,  256, 0, stream>>>(x, mhist);
    k_medsel<<<48,   256, 0, stream>>>(mhist, kern, s1d, med);
    k_conv  <<<3072, 512, 0, stream>>>(x, mask, med, s1d, res16, phist);
    k_pct   <<<48,   256, 0, stream>>>(phist, lohi);
    k_final <<<6144, 256, 0, stream>>>(res16, lohi, out);
}

// Round 6
// 183.843 us; speedup vs baseline: 1.5206x; 1.4608x over previous
//
#include <hip/hip_runtime.h>
#include <hip/hip_fp16.h>

// Problem constants
#define W 512
#define H 512
#define HW (512*512)          // 262144 = 2^18
#define NCH 3
#define MBINS 4096            // median histogram bins over [0,1)
#define PBINS 1024            // percentile histogram bins, value = (bin-512)/256
#define MEDK ((HW-1)/2)       // 131071, 0-indexed lower-median rank
#define KW 23                 // filter width
#define KR 11                 // radius

// conv tile geometry
#define TR 32                 // output rows per block
#define TC 128                // output cols per block
#define SR (TR + 2*KR)        // 54 staged rows
#define SC (TC + 2*KR)        // 150 staged cols
#define FSTR2 154             // fill stride in halves (154/2=77 dwords, 77%32=13 coprime)
#define HSTR2 65              // hbuf stride in half2 (65%32=1 -> banks spread by row)
#define NQ 38                 // float4 quads per staged row: [c0-12, c0+140)
#define NSLOT (SR*NQ)         // 2052 stage slots
#define HBLK 16               // k_hist blocks per group
#define CBLK 64               // k_conv blocks per group
#define SENT 0x7C00u          // f16 +inf sentinel: "mask==0 here"

typedef float f32x2 __attribute__((ext_vector_type(2)));

// ------- median histogram: batched loads (8 float4 in flight), private store -------
__global__ __launch_bounds__(256) void k_hist(const float* __restrict__ x,
                                              unsigned int* __restrict__ hist) {
    __shared__ unsigned int h[MBINS];
    int g = blockIdx.x >> 4;        // 16 blocks per group
    int chunk = blockIdx.x & 15;    // 16384 elems per block
    for (int i = threadIdx.x; i < MBINS; i += 256) h[i] = 0u;
    __syncthreads();
    const float4* xp = (const float4*)(x + (size_t)g*HW + (size_t)chunk*16384);
    #pragma unroll
    for (int hb = 0; hb < 2; ++hb) {
        float4 v[8];
        #pragma unroll
        for (int it = 0; it < 8; ++it) v[it] = xp[(hb*8 + it)*256 + threadIdx.x];
        #pragma unroll
        for (int it = 0; it < 8; ++it) {
            int b0 = min(MBINS-1, (int)(v[it].x * (float)MBINS));
            int b1 = min(MBINS-1, (int)(v[it].y * (float)MBINS));
            int b2 = min(MBINS-1, (int)(v[it].z * (float)MBINS));
            int b3 = min(MBINS-1, (int)(v[it].w * (float)MBINS));
            atomicAdd(&h[b0], 1u); atomicAdd(&h[b1], 1u);
            atomicAdd(&h[b2], 1u); atomicAdd(&h[b3], 1u);
        }
    }
    __syncthreads();
    unsigned int* gh = hist + (size_t)blockIdx.x*MBINS;   // private slice
    for (int i = threadIdx.x; i < MBINS; i += 256) gh[i] = h[i];
}

// ------ median select (+ kernel-row-sum prep in block 0): sum, scan, rank ------
__global__ __launch_bounds__(256) void k_medsel(const unsigned int* __restrict__ hist,
                                                const float* __restrict__ kern,
                                                float* __restrict__ s1d,
                                                float* __restrict__ med) {
    __shared__ unsigned int scan[256];
    const int g = blockIdx.x;
    const int tid = threadIdx.x;
    if (g == 0 && tid < KW) {       // separable factor: row sums of 2D kernel
        float s = 0.f;
        for (int j = 0; j < KW; ++j) s += kern[tid*KW + j];
        s1d[tid] = s;
    }
    unsigned int local[16];
    #pragma unroll
    for (int i = 0; i < 16; ++i) local[i] = 0u;
    for (int c = 0; c < HBLK; ++c) {
        const uint4* p = (const uint4*)(hist + ((size_t)(g*HBLK + c))*MBINS + tid*16);
        #pragma unroll
        for (int q = 0; q < 4; ++q) {
            uint4 v = p[q];
            local[q*4+0] += v.x; local[q*4+1] += v.y;
            local[q*4+2] += v.z; local[q*4+3] += v.w;
        }
    }
    unsigned int s = 0;
    #pragma unroll
    for (int i = 0; i < 16; ++i) s += local[i];
    scan[tid] = s;
    __syncthreads();
    #pragma unroll
    for (int off = 1; off < 256; off <<= 1) {
        unsigned int t = (tid >= off) ? scan[tid - off] : 0u;
        __syncthreads();
        scan[tid] += t;
        __syncthreads();
    }
    unsigned int p = scan[tid] - s;
    if (p <= (unsigned)MEDK && (unsigned)MEDK < p + s) {   // unique owner thread
        unsigned int c = p;
        #pragma unroll
        for (int i = 0; i < 16; ++i) {
            if (c + local[i] > (unsigned)MEDK) {
                int bin = tid*16 + i;
                float frac = ((float)(MEDK - c) + 0.5f) / (float)local[i];
                med[g] = ((float)bin + frac) * (1.0f/(float)MBINS) + 0.2f;
                break;
            }
            c += local[i];
        }
    }
}

// Stage helper: load one (row, quad) slot and write 4 f16 fill values.
__device__ __forceinline__ void stage_slot(int slot, int r0, int c0, float medv,
                                           const float* __restrict__ xg,
                                           const float* __restrict__ mg,
                                           __half* __restrict__ fillh) {
    const int row = slot / NQ;
    const int q   = slot - row*NQ;
    const int gr  = r0 + row - KR;
    const int gc0q = c0 - 12 + q*4;
    const bool rowok = (unsigned)gr < (unsigned)H;
    float4 xv = {0.f,0.f,0.f,0.f}, mv = {0.f,0.f,0.f,0.f};
    if (rowok) {
        if (gc0q >= 0 && gc0q <= W-4) {
            xv = *(const float4*)(xg + gr*W + gc0q);
            mv = *(const float4*)(mg + gr*W + gc0q);
        } else {
            float* xe = (float*)&xv; float* me = (float*)&mv;
            #pragma unroll
            for (int e = 0; e < 4; ++e) {
                int gc = gc0q + e;
                if ((unsigned)gc < (unsigned)W) {
                    xe[e] = xg[gr*W + gc]; me[e] = mg[gr*W + gc];
                }
            }
        }
    }
    const float* xe = (const float*)&xv; const float* me = (const float*)&mv;
    #pragma unroll
    for (int e = 0; e < 4; ++e) {
        const int gc = gc0q + e;
        const int lc = gc - (c0 - KR);
        if (lc >= 0 && lc < SC) {
            float f = 0.f;
            if (rowok && (unsigned)gc < (unsigned)W)
                f = me[e]*xe[e] + (1.f - me[e])*medv;
            fillh[row*FSTR2 + lc] = __float2half(f);
        }
    }
}

// ---- fused separable conv: stage(f16) -> h-pass -> v-pass, scatter-accumulate ----
// Scatter form: stream each input once, accumulate into 4 x f32x2 (pk-fma),
// ~16 live regs per phase instead of a 30-deep window. 3 barriers.
__global__ __launch_bounds__(512) void k_conv(const float* __restrict__ x,
                                              const float* __restrict__ mask,
                                              const float* __restrict__ med,
                                              const float* __restrict__ s1d,
                                              unsigned short* __restrict__ res,
                                              unsigned int* __restrict__ phist) {
    __shared__ __half fillh[SR*FSTR2];    // 16632 B
    __shared__ __half2 hbuf2[SR*HSTR2];   // 14040 B
    __shared__ float sk[KW];
    __shared__ unsigned int h[PBINS];     // 4096 B
    const int b   = blockIdx.x;
    const int g   = b >> 6;               // 48 groups
    const int sub = b & 63;
    const int rb  = sub >> 2;             // 16 row bands
    const int cb  = sub & 3;              // 4 col bands
    const int r0  = rb*TR, c0 = cb*TC;
    const int n   = g / NCH;
    const int tid = threadIdx.x;
    for (int i = tid; i < PBINS; i += 512) h[i] = 0u;
    if (tid < KW) sk[tid] = s1d[tid];
    const float medv = med[g];
    const float* xg = x    + (size_t)g*HW;
    const float* mg = mask + (size_t)n*HW;

    // ---- stage: batched loads (4 slots = 8 float4 in flight), f16 fill ----
    {
        float4 xa[4], ma[4];
        #pragma unroll
        for (int s = 0; s < 4; ++s) {
            const int slot = tid + s*512;
            const int row = slot / NQ;
            const int q   = slot - row*NQ;
            const int gr  = r0 + row - KR;
            const int gc0q = c0 - 12 + q*4;
            const bool rowok = (unsigned)gr < (unsigned)H;
            float4 xv = {0.f,0.f,0.f,0.f}, mv = {0.f,0.f,0.f,0.f};
            if (rowok) {
                if (gc0q >= 0 && gc0q <= W-4) {
                    xv = *(const float4*)(xg + gr*W + gc0q);
                    mv = *(const float4*)(mg + gr*W + gc0q);
                } else {
                    float* xe = (float*)&xv; float* me = (float*)&mv;
                    #pragma unroll
                    for (int e = 0; e < 4; ++e) {
                        int gc = gc0q + e;
                        if ((unsigned)gc < (unsigned)W) {
                            xe[e] = xg[gr*W + gc]; me[e] = mg[gr*W + gc];
                        }
                    }
                }
            }
            xa[s] = xv; ma[s] = mv;
        }
        #pragma unroll
        for (int s = 0; s < 4; ++s) {
            const int slot = tid + s*512;
            const int row = slot / NQ;
            const int q   = slot - row*NQ;
            const int gr  = r0 + row - KR;
            const int gc0q = c0 - 12 + q*4;
            const bool rowok = (unsigned)gr < (unsigned)H;
            const float* xe = (const float*)&xa[s];
            const float* me = (const float*)&ma[s];
            #pragma unroll
            for (int e = 0; e < 4; ++e) {
                const int gc = gc0q + e;
                const int lc = gc - (c0 - KR);
                if (lc >= 0 && lc < SC) {
                    float f = 0.f;
                    if (rowok && (unsigned)gc < (unsigned)W)
                        f = me[e]*xe[e] + (1.f - me[e])*medv;
                    fillh[row*FSTR2 + lc] = __float2half(f);
                }
            }
        }
        if (tid < NSLOT - 2048)   // 4 tail slots
            stage_slot(2048 + tid, r0, c0, medv, xg, mg, fillh);
    }
    __syncthreads();

    // ---- h-pass: thread=(row 0..53, col-group); stream 30 f16, scatter into 4xf32x2 ----
    {
        const int row = tid & 63;
        const int cg  = tid >> 6;            // 0..7
        if (row < SR) {
            const __half2* fill2 = (const __half2*)fillh;
            #pragma unroll
            for (int half = 0; half < 2; ++half) {
                const int cg8 = cg + half*8;            // 0..15
                const int f2base = row*(FSTR2/2) + cg8*4;
                f32x2 acc[4] = {{0.f,0.f},{0.f,0.f},{0.f,0.f},{0.f,0.f}};
                #pragma unroll
                for (int t = 0; t < 15; ++t) {
                    const __half2 hp = fill2[f2base + t];
                    #pragma unroll
                    for (int u = 0; u < 2; ++u) {
                        const float v = u ? __high2float(hp) : __low2float(hp);
                        const int j = 2*t + u;
                        #pragma unroll
                        for (int p = 0; p < 4; ++p) {
                            const int d = j - 2*p;       // compile-time
                            if (d >= 1 && d <= 22) {
                                f32x2 kk = {sk[d], sk[d-1]};
                                acc[p] += kk * v;
                            } else if (d == 0) {
                                acc[p].x += sk[0]*v;
                            } else if (d == 23) {
                                acc[p].y += sk[22]*v;
                            }
                        }
                    }
                }
                #pragma unroll
                for (int p = 0; p < 4; ++p)
                    hbuf2[row*HSTR2 + cg8*4 + p] = __floats2half2_rn(acc[p].x, acc[p].y);
            }
        }
    }
    __syncthreads();

    // ---- v-pass: thread=(col, 8-row group); stream 30 rows, scatter; res + hist ----
    {
        const int col = tid & 127;
        const int rg  = tid >> 7;            // 0..3
        const int lr0 = rg*8;
        const __half* hb = (const __half*)hbuf2;   // row stride 2*HSTR2 halves
        f32x2 acc[4] = {{0.f,0.f},{0.f,0.f},{0.f,0.f},{0.f,0.f}};
        #pragma unroll
        for (int j = 0; j < 30; ++j) {
            const float v = __half2float(hb[(lr0 + j)*(2*HSTR2) + col]);
            #pragma unroll
            for (int p = 0; p < 4; ++p) {
                const int d = j - 2*p;
                if (d >= 1 && d <= 22) {
                    f32x2 kk = {sk[d], sk[d-1]};
                    acc[p] += kk * v;
                } else if (d == 0) {
                    acc[p].x += sk[0]*v;
                } else if (d == 23) {
                    acc[p].y += sk[22]*v;
                }
            }
        }
        unsigned short* rout = res + (size_t)g*HW;
        #pragma unroll
        for (int o = 0; o < 8; ++o) {
            const float blur = (o & 1) ? acc[o>>1].y : acc[o>>1].x;
            const float fv = __half2float(fillh[(lr0 + o + KR)*FSTR2 + col + KR]);
            const float rv = fv - blur;
            const int r = r0 + lr0 + o;
            const float mv = mg[r*W + c0 + col];
            rout[r*W + c0 + col] =
                (mv != 0.f) ? __half_as_ushort(__float2half(rv)) : (unsigned short)SENT;
            int bin = (int)truncf(rv*256.f) + 512;
            bin = min(PBINS-1, max(0, bin));
            atomicAdd(&h[bin], 1u);
        }
    }
    __syncthreads();
    unsigned int* gh = phist + (size_t)b*PBINS;    // private slice, plain stores
    for (int i = tid; i < PBINS; i += 512) gh[i] = h[i];
}

// ------ percentile select: sum 64 private hists, parallel scan + rank lookup ------
__global__ __launch_bounds__(256) void k_pct(const unsigned int* __restrict__ phist,
                                             float* __restrict__ lohi) {
    __shared__ unsigned int scan[256];
    __shared__ float vsh[4];
    const int g = blockIdx.x;
    const int tid = threadIdx.x;
    unsigned int local[4];
    #pragma unroll
    for (int i = 0; i < 4; ++i) local[i] = 0u;
    for (int c = 0; c < CBLK; ++c) {
        uint4 v = *(const uint4*)(phist + ((size_t)(g*CBLK + c))*PBINS + tid*4);
        local[0] += v.x; local[1] += v.y; local[2] += v.z; local[3] += v.w;
    }
    unsigned int s = local[0] + local[1] + local[2] + local[3];
    scan[tid] = s;
    __syncthreads();
    #pragma unroll
    for (int off = 1; off < 256; off <<= 1) {
        unsigned int t = (tid >= off) ? scan[tid - off] : 0u;
        __syncthreads();
        scan[tid] += t;
        __syncthreads();
    }
    unsigned int p = scan[tid] - s;   // exclusive prefix
    const double dl = (3.0/100.0)*(double)(HW-1);    // 7864.29
    const double dh = (97.0/100.0)*(double)(HW-1);   // 254278.71
    const long il = (long)dl, ih = (long)dh;
    const long ranks[4] = {il, il+1, ih, ih+1};
    #pragma unroll
    for (int ri = 0; ri < 4; ++ri) {
        long r = ranks[ri];
        if ((long)p <= r && r < (long)(p + s)) {     // owner thread for this rank
            unsigned int c = p;
            #pragma unroll
            for (int i = 0; i < 4; ++i) {
                if ((long)(c + local[i]) > r) {
                    vsh[ri] = (float)(tid*4 + i - 512) * (1.0f/256.0f);
                    break;
                }
                c += local[i];
            }
        }
    }
    __syncthreads();
    if (tid == 0) {
        double fl = dl - (double)il, fh = dh - (double)ih;
        double lo = (double)vsh[0] + fl*((double)vsh[1] - (double)vsh[0]);
        double hi = (double)vsh[2] + fh*((double)vsh[3] - (double)vsh[2]);
        lohi[2*g]   = (float)lo;
        lohi[2*g+1] = (float)hi;
    }
}

// ---- final: out = sentinel ? 0 : (res_f16 - lo)/(hi - lo); no mask read ----
__global__ __launch_bounds__(256) void k_final(const unsigned short* __restrict__ res,
                                               const float* __restrict__ lohi,
                                               float* __restrict__ out) {
    size_t idx8 = (size_t)blockIdx.x*256 + threadIdx.x;   // 1,572,864 total
    size_t base = idx8*8;
    int g = (int)(base >> 18);
    float lo = lohi[2*g], hi = lohi[2*g+1];
    float inv = 1.0f/(hi - lo);
    uint4 rbits = *(const uint4*)(res + base);            // 8 ushorts
    const unsigned short* u = (const unsigned short*)&rbits;
    float4 o0, o1;
    float* po0 = (float*)&o0;
    float* po1 = (float*)&o1;
    #pragma unroll
    for (int e = 0; e < 4; ++e)
        po0[e] = (u[e] == (unsigned short)SENT)
                   ? 0.f : (__half2float(__ushort_as_half(u[e])) - lo)*inv;
    #pragma unroll
    for (int e = 0; e < 4; ++e)
        po1[e] = (u[4+e] == (unsigned short)SENT)
                   ? 0.f : (__half2float(__ushort_as_half(u[4+e])) - lo)*inv;
    *(float4*)(out + base)     = o0;
    *(float4*)(out + base + 4) = o1;
}

extern "C" void kernel_launch(void* const* d_in, const int* in_sizes, int n_in,
                              void* d_out, int out_size, void* d_ws, size_t ws_size,
                              hipStream_t stream) {
    const float* x    = (const float*)d_in[0];   // [16,3,512,512] f32
    const float* mask = (const float*)d_in[1];   // [16,1,512,512] f32
    const float* kern = (const float*)d_in[2];   // [23,23] f32
    float* out = (float*)d_out;

    char* ws = (char*)d_ws;
    // Workspace layout (~50.4 MB, all write-before-read -> no memset needed):
    //   [0, 12582912)            phist : 3072 private 1024-bin u32 hists
    //   [12582912, 25165824)     mhist : 768 private 4096-bin u32 hists
    //   [25165824, 50331648)     res16 : 12.58M ushort (f16 residual / inf sentinel)
    //   [50331648, +192)         med   : 48 f32
    //   [50331904, +92)          s1d   : 23 f32
    //   [50332160, +384)         lohi  : 96 f32
    unsigned int*   phist = (unsigned int*)ws;
    unsigned int*   mhist = (unsigned int*)(ws + 12582912);
    unsigned short* res16 = (unsigned short*)(ws + 25165824);
    float* med  = (float*)(ws + 50331648);
    float* s1d  = (float*)(ws + 50331904);
    float* lohi = (float*)(ws + 50332160);

    k_hist  <<<768,  256, 0, stream>>>(x, mhist);
    k_medsel<<<48,   256, 0, stream>>>(mhist, kern, s1d, med);
    k_conv  <<<3072, 512, 0, stream>>>(x, mask, med, s1d, res16, phist);
    k_pct   <<<48,   256, 0, stream>>>(phist, lohi);
    k_final <<<6144, 256, 0, stream>>>(res16, lohi, out);
}

// Round 7
// 173.980 us; speedup vs baseline: 1.6068x; 1.0567x over previous
//
#include <hip/hip_runtime.h>
#include <hip/hip_fp16.h>

// Problem constants
#define W 512
#define H 512
#define HW (512*512)          // 262144 = 2^18
#define NCH 3
#define MBINS 4096            // median histogram bins over [0,1)
#define PBINS 1024            // percentile histogram bins, value = (bin-512)/256
#define MEDK ((HW-1)/2)       // 131071, 0-indexed lower-median rank
#define KW 23                 // filter width
#define KR 11                 // radius

// conv tile geometry
#define TR 32                 // output rows per block
#define TC 128                // output cols per block
#define SR (TR + 2*KR)        // 54 staged rows
#define SC (TC + 2*KR)        // 150 staged cols
#define FSTR2 154             // fill stride in halves (154/2=77 dwords, 77%32=13 coprime)
#define TSTR 66               // hbT stride in halves per col (33 dwords, 33%32=1)
#define NQ 38                 // float4 quads per staged row: [c0-12, c0+140)
#define NSLOT (SR*NQ)         // 2052 stage slots
#define HBLK 16               // k_hist blocks per group
#define CBLK 64               // k_conv blocks per group
#define SENT 0x7C00u          // f16 +inf sentinel: "mask==0 here"

typedef _Float16 h16x2 __attribute__((ext_vector_type(2)));

// v_dot2_f32_f16: 2 f16 MACs per op, f32 accumulate (full-rate on CDNA)
static __device__ __forceinline__ float fdot2h(__half2 a, __half2 b, float c) {
#if __has_builtin(__builtin_amdgcn_fdot2)
    return __builtin_amdgcn_fdot2(__builtin_bit_cast(h16x2, a),
                                  __builtin_bit_cast(h16x2, b), c, false);
#else
    return fmaf(__high2float(a), __high2float(b),
           fmaf(__low2float(a),  __low2float(b),  c));
#endif
}

// 8 consecutive conv outputs from 15 half2 words (30 input halves), dot2 form.
// Even output k (s=k/2):   taps j=0..21 as words w[s..s+10] * skE, tail sk22*lo(w[s+11])
// Odd  output k (s=(k-1)/2): taps j=1..22 as words w[s+1..s+11] * skO, head sk0*hi(w[s])
static __device__ __forceinline__ void conv8_dot2(const __half2 (&w)[15],
                                                  const __half2 (&eK)[11],
                                                  const __half2 (&oK)[11],
                                                  float sk0f, float sk22f,
                                                  float (&out8)[8]) {
    #pragma unroll
    for (int k = 0; k < 8; k += 2) {
        const int s = k >> 1;
        float accE = 0.f, accO = 0.f;
        #pragma unroll
        for (int jj = 0; jj < 11; ++jj) {
            accE = fdot2h(w[s+jj],   eK[jj], accE);
            accO = fdot2h(w[s+1+jj], oK[jj], accO);
        }
        accE += sk22f * __low2float(w[s+11]);
        accO += sk0f  * __high2float(w[s]);
        out8[k]   = accE;
        out8[k+1] = accO;
    }
}

// ------- median histogram: batched loads (8 float4 in flight), private store -------
__global__ __launch_bounds__(256) void k_hist(const float* __restrict__ x,
                                              unsigned int* __restrict__ hist) {
    __shared__ unsigned int h[MBINS];
    int g = blockIdx.x >> 4;        // 16 blocks per group
    int chunk = blockIdx.x & 15;    // 16384 elems per block
    for (int i = threadIdx.x; i < MBINS; i += 256) h[i] = 0u;
    __syncthreads();
    const float4* xp = (const float4*)(x + (size_t)g*HW + (size_t)chunk*16384);
    #pragma unroll
    for (int hb = 0; hb < 2; ++hb) {
        float4 v[8];
        #pragma unroll
        for (int it = 0; it < 8; ++it) v[it] = xp[(hb*8 + it)*256 + threadIdx.x];
        #pragma unroll
        for (int it = 0; it < 8; ++it) {
            int b0 = min(MBINS-1, (int)(v[it].x * (float)MBINS));
            int b1 = min(MBINS-1, (int)(v[it].y * (float)MBINS));
            int b2 = min(MBINS-1, (int)(v[it].z * (float)MBINS));
            int b3 = min(MBINS-1, (int)(v[it].w * (float)MBINS));
            atomicAdd(&h[b0], 1u); atomicAdd(&h[b1], 1u);
            atomicAdd(&h[b2], 1u); atomicAdd(&h[b3], 1u);
        }
    }
    __syncthreads();
    unsigned int* gh = hist + (size_t)blockIdx.x*MBINS;   // private slice
    for (int i = threadIdx.x; i < MBINS; i += 256) gh[i] = h[i];
}

// ------ median select (+ kernel-row-sum prep in block 0): sum (unrolled), scan, rank ------
__global__ __launch_bounds__(256) void k_medsel(const unsigned int* __restrict__ hist,
                                                const float* __restrict__ kern,
                                                float* __restrict__ s1d,
                                                float* __restrict__ med) {
    __shared__ unsigned int scan[256];
    const int g = blockIdx.x;
    const int tid = threadIdx.x;
    if (g == 0 && tid < KW) {       // separable factor: row sums of 2D kernel
        float s = 0.f;
        for (int j = 0; j < KW; ++j) s += kern[tid*KW + j];
        s1d[tid] = s;
    }
    unsigned int local[16];
    #pragma unroll
    for (int i = 0; i < 16; ++i) local[i] = 0u;
    for (int c = 0; c < HBLK; c += 4) {       // 16 uint4 loads in flight
        uint4 v[4][4];
        #pragma unroll
        for (int cc = 0; cc < 4; ++cc) {
            const uint4* p = (const uint4*)(hist + ((size_t)(g*HBLK + c + cc))*MBINS + tid*16);
            #pragma unroll
            for (int q = 0; q < 4; ++q) v[cc][q] = p[q];
        }
        #pragma unroll
        for (int cc = 0; cc < 4; ++cc) {
            #pragma unroll
            for (int q = 0; q < 4; ++q) {
                local[q*4+0] += v[cc][q].x; local[q*4+1] += v[cc][q].y;
                local[q*4+2] += v[cc][q].z; local[q*4+3] += v[cc][q].w;
            }
        }
    }
    unsigned int s = 0;
    #pragma unroll
    for (int i = 0; i < 16; ++i) s += local[i];
    scan[tid] = s;
    __syncthreads();
    #pragma unroll
    for (int off = 1; off < 256; off <<= 1) {
        unsigned int t = (tid >= off) ? scan[tid - off] : 0u;
        __syncthreads();
        scan[tid] += t;
        __syncthreads();
    }
    unsigned int p = scan[tid] - s;
    if (p <= (unsigned)MEDK && (unsigned)MEDK < p + s) {   // unique owner thread
        unsigned int c = p;
        #pragma unroll
        for (int i = 0; i < 16; ++i) {
            if (c + local[i] > (unsigned)MEDK) {
                int bin = tid*16 + i;
                float frac = ((float)(MEDK - c) + 0.5f) / (float)local[i];
                med[g] = ((float)bin + frac) * (1.0f/(float)MBINS) + 0.2f;
                break;
            }
            c += local[i];
        }
    }
}

// Stage helper: load one (row, quad) slot and write 4 f16 fill values.
__device__ __forceinline__ void stage_slot(int slot, int r0, int c0, float medv,
                                           const float* __restrict__ xg,
                                           const float* __restrict__ mg,
                                           __half* __restrict__ fillh) {
    const int row = slot / NQ;
    const int q   = slot - row*NQ;
    const int gr  = r0 + row - KR;
    const int gc0q = c0 - 12 + q*4;
    const bool rowok = (unsigned)gr < (unsigned)H;
    float4 xv = {0.f,0.f,0.f,0.f}, mv = {0.f,0.f,0.f,0.f};
    if (rowok) {
        if (gc0q >= 0 && gc0q <= W-4) {
            xv = *(const float4*)(xg + gr*W + gc0q);
            mv = *(const float4*)(mg + gr*W + gc0q);
        } else {
            float* xe = (float*)&xv; float* me = (float*)&mv;
            #pragma unroll
            for (int e = 0; e < 4; ++e) {
                int gc = gc0q + e;
                if ((unsigned)gc < (unsigned)W) {
                    xe[e] = xg[gr*W + gc]; me[e] = mg[gr*W + gc];
                }
            }
        }
    }
    const float* xe = (const float*)&xv; const float* me = (const float*)&mv;
    #pragma unroll
    for (int e = 0; e < 4; ++e) {
        const int gc = gc0q + e;
        const int lc = gc - (c0 - KR);
        if (lc >= 0 && lc < SC) {
            float f = 0.f;
            if (rowok && (unsigned)gc < (unsigned)W)
                f = me[e]*xe[e] + (1.f - me[e])*medv;
            fillh[row*FSTR2 + lc] = __float2half(f);
        }
    }
}

// ---- fused separable conv: stage(f16) -> h-pass(dot2) -> v-pass(dot2 on transposed) ----
__global__ __launch_bounds__(512) void k_conv(const float* __restrict__ x,
                                              const float* __restrict__ mask,
                                              const float* __restrict__ med,
                                              const float* __restrict__ s1d,
                                              unsigned short* __restrict__ res,
                                              unsigned int* __restrict__ phist) {
    __shared__ __half fillh[SR*FSTR2];    // 16632 B
    __shared__ __half hbT[TC*TSTR];       // 16896 B, transposed: [col][row], stride 66
    __shared__ __half2 skE[11], skO[11];  // even/odd-phase f16 tap pairs
    __shared__ float sk0f_s, sk22f_s;
    __shared__ unsigned int h[PBINS];     // 4096 B
    const int b   = blockIdx.x;
    const int g   = b >> 6;               // 48 groups
    const int sub = b & 63;
    const int rb  = sub >> 2;             // 16 row bands
    const int cb  = sub & 3;              // 4 col bands
    const int r0  = rb*TR, c0 = cb*TC;
    const int n   = g / NCH;
    const int tid = threadIdx.x;
    for (int i = tid; i < PBINS; i += 512) h[i] = 0u;
    if (tid < 11) {
        skE[tid] = __floats2half2_rn(s1d[2*tid],   s1d[2*tid+1]);
        skO[tid] = __floats2half2_rn(s1d[2*tid+1], s1d[2*tid+2]);
    }
    if (tid == 11) { sk0f_s = s1d[0]; sk22f_s = s1d[22]; }
    const float medv = med[g];
    const float* xg = x    + (size_t)g*HW;
    const float* mg = mask + (size_t)n*HW;

    // ---- stage: batched loads (4 slots = 8 float4 in flight), f16 fill ----
    {
        float4 xa[4], ma[4];
        #pragma unroll
        for (int s = 0; s < 4; ++s) {
            const int slot = tid + s*512;
            const int row = slot / NQ;
            const int q   = slot - row*NQ;
            const int gr  = r0 + row - KR;
            const int gc0q = c0 - 12 + q*4;
            const bool rowok = (unsigned)gr < (unsigned)H;
            float4 xv = {0.f,0.f,0.f,0.f}, mv = {0.f,0.f,0.f,0.f};
            if (rowok) {
                if (gc0q >= 0 && gc0q <= W-4) {
                    xv = *(const float4*)(xg + gr*W + gc0q);
                    mv = *(const float4*)(mg + gr*W + gc0q);
                } else {
                    float* xe = (float*)&xv; float* me = (float*)&mv;
                    #pragma unroll
                    for (int e = 0; e < 4; ++e) {
                        int gc = gc0q + e;
                        if ((unsigned)gc < (unsigned)W) {
                            xe[e] = xg[gr*W + gc]; me[e] = mg[gr*W + gc];
                        }
                    }
                }
            }
            xa[s] = xv; ma[s] = mv;
        }
        #pragma unroll
        for (int s = 0; s < 4; ++s) {
            const int slot = tid + s*512;
            const int row = slot / NQ;
            const int q   = slot - row*NQ;
            const int gr  = r0 + row - KR;
            const int gc0q = c0 - 12 + q*4;
            const bool rowok = (unsigned)gr < (unsigned)H;
            const float* xe = (const float*)&xa[s];
            const float* me = (const float*)&ma[s];
            #pragma unroll
            for (int e = 0; e < 4; ++e) {
                const int gc = gc0q + e;
                const int lc = gc - (c0 - KR);
                if (lc >= 0 && lc < SC) {
                    float f = 0.f;
                    if (rowok && (unsigned)gc < (unsigned)W)
                        f = me[e]*xe[e] + (1.f - me[e])*medv;
                    fillh[row*FSTR2 + lc] = __float2half(f);
                }
            }
        }
        if (tid < NSLOT - 2048)   // 4 tail slots
            stage_slot(2048 + tid, r0, c0, medv, xg, mg, fillh);
    }
    __syncthreads();

    // copy taps LDS -> regs once (broadcast reads)
    __half2 eK[11], oK[11];
    #pragma unroll
    for (int jj = 0; jj < 11; ++jj) { eK[jj] = skE[jj]; oK[jj] = skO[jj]; }
    const float sk0f = sk0f_s, sk22f = sk22f_s;

    // ---- h-pass: thread=(row 0..53, col-group of 8); 15 half2 words -> 8 outputs ----
    // writes TRANSPOSED hbT[col][row]: wave lanes differ in row -> contiguous halves, no conflict
    {
        const int row = tid & 63;
        const int cg  = tid >> 6;            // 0..7
        if (row < SR) {
            const __half2* fill2 = (const __half2*)fillh;
            #pragma unroll
            for (int half = 0; half < 2; ++half) {
                const int cg8 = cg + half*8;            // 0..15
                __half2 w[15];
                #pragma unroll
                for (int t = 0; t < 15; ++t) w[t] = fill2[row*(FSTR2/2) + cg8*4 + t];
                float out8[8];
                conv8_dot2(w, eK, oK, sk0f, sk22f, out8);
                #pragma unroll
                for (int k = 0; k < 8; ++k)
                    hbT[(cg8*8 + k)*TSTR + row] = __float2half(out8[k]);
            }
        }
    }
    __syncthreads();

    // ---- v-pass: thread=(col, 8-row group); row-contiguous reads from hbT; res + hist ----
    {
        const int col = tid & 127;
        const int rg  = tid >> 7;            // 0..3
        const int lr0 = rg*8;
        const __half2* hb2 = (const __half2*)hbT;
        __half2 w[15];
        #pragma unroll
        for (int t = 0; t < 15; ++t) w[t] = hb2[col*(TSTR/2) + (lr0 >> 1) + t];
        float out8[8];
        conv8_dot2(w, eK, oK, sk0f, sk22f, out8);
        unsigned short* rout = res + (size_t)g*HW;
        #pragma unroll
        for (int o = 0; o < 8; ++o) {
            const float fv = __half2float(fillh[(lr0 + o + KR)*FSTR2 + col + KR]);
            const float rv = fv - out8[o];
            const int r = r0 + lr0 + o;
            const float mv = mg[r*W + c0 + col];
            rout[r*W + c0 + col] =
                (mv != 0.f) ? __half_as_ushort(__float2half(rv)) : (unsigned short)SENT;
            int bin = (int)truncf(rv*256.f) + 512;
            bin = min(PBINS-1, max(0, bin));
            atomicAdd(&h[bin], 1u);
        }
    }
    __syncthreads();
    unsigned int* gh = phist + (size_t)b*PBINS;    // private slice, plain stores
    for (int i = tid; i < PBINS; i += 512) gh[i] = h[i];
}

// ------ percentile select: sum 64 private hists (unrolled x8), scan + rank lookup ------
__global__ __launch_bounds__(256) void k_pct(const unsigned int* __restrict__ phist,
                                             float* __restrict__ lohi) {
    __shared__ unsigned int scan[256];
    __shared__ float vsh[4];
    const int g = blockIdx.x;
    const int tid = threadIdx.x;
    unsigned int local[4];
    #pragma unroll
    for (int i = 0; i < 4; ++i) local[i] = 0u;
    for (int c = 0; c < CBLK; c += 8) {      // 8 uint4 loads in flight
        uint4 v[8];
        #pragma unroll
        for (int cc = 0; cc < 8; ++cc)
            v[cc] = *(const uint4*)(phist + ((size_t)(g*CBLK + c + cc))*PBINS + tid*4);
        #pragma unroll
        for (int cc = 0; cc < 8; ++cc) {
            local[0] += v[cc].x; local[1] += v[cc].y;
            local[2] += v[cc].z; local[3] += v[cc].w;
        }
    }
    unsigned int s = local[0] + local[1] + local[2] + local[3];
    scan[tid] = s;
    __syncthreads();
    #pragma unroll
    for (int off = 1; off < 256; off <<= 1) {
        unsigned int t = (tid >= off) ? scan[tid - off] : 0u;
        __syncthreads();
        scan[tid] += t;
        __syncthreads();
    }
    unsigned int p = scan[tid] - s;   // exclusive prefix
    const double dl = (3.0/100.0)*(double)(HW-1);    // 7864.29
    const double dh = (97.0/100.0)*(double)(HW-1);   // 254278.71
    const long il = (long)dl, ih = (long)dh;
    const long ranks[4] = {il, il+1, ih, ih+1};
    #pragma unroll
    for (int ri = 0; ri < 4; ++ri) {
        long r = ranks[ri];
        if ((long)p <= r && r < (long)(p + s)) {     // owner thread for this rank
            unsigned int c = p;
            #pragma unroll
            for (int i = 0; i < 4; ++i) {
                if ((long)(c + local[i]) > r) {
                    vsh[ri] = (float)(tid*4 + i - 512) * (1.0f/256.0f);
                    break;
                }
                c += local[i];
            }
        }
    }
    __syncthreads();
    if (tid == 0) {
        double fl = dl - (double)il, fh = dh - (double)ih;
        double lo = (double)vsh[0] + fl*((double)vsh[1] - (double)vsh[0]);
        double hi = (double)vsh[2] + fh*((double)vsh[3] - (double)vsh[2]);
        lohi[2*g]   = (float)lo;
        lohi[2*g+1] = (float)hi;
    }
}

// ---- final: out = sentinel ? 0 : (res_f16 - lo)/(hi - lo); no mask read ----
__global__ __launch_bounds__(256) void k_final(const unsigned short* __restrict__ res,
                                               const float* __restrict__ lohi,
                                               float* __restrict__ out) {
    size_t idx8 = (size_t)blockIdx.x*256 + threadIdx.x;   // 1,572,864 total
    size_t base = idx8*8;
    int g = (int)(base >> 18);
    float lo = lohi[2*g], hi = lohi[2*g+1];
    float inv = 1.0f/(hi - lo);
    uint4 rbits = *(const uint4*)(res + base);            // 8 ushorts
    const unsigned short* u = (const unsigned short*)&rbits;
    float4 o0, o1;
    float* po0 = (float*)&o0;
    float* po1 = (float*)&o1;
    #pragma unroll
    for (int e = 0; e < 4; ++e)
        po0[e] = (u[e] == (unsigned short)SENT)
                   ? 0.f : (__half2float(__ushort_as_half(u[e])) - lo)*inv;
    #pragma unroll
    for (int e = 0; e < 4; ++e)
        po1[e] = (u[4+e] == (unsigned short)SENT)
                   ? 0.f : (__half2float(__ushort_as_half(u[4+e])) - lo)*inv;
    *(float4*)(out + base)     = o0;
    *(float4*)(out + base + 4) = o1;
}

extern "C" void kernel_launch(void* const* d_in, const int* in_sizes, int n_in,
                              void* d_out, int out_size, void* d_ws, size_t ws_size,
                              hipStream_t stream) {
    const float* x    = (const float*)d_in[0];   // [16,3,512,512] f32
    const float* mask = (const float*)d_in[1];   // [16,1,512,512] f32
    const float* kern = (const float*)d_in[2];   // [23,23] f32
    float* out = (float*)d_out;

    char* ws = (char*)d_ws;
    // Workspace layout (~50.4 MB, all write-before-read -> no memset needed):
    //   [0, 12582912)            phist : 3072 private 1024-bin u32 hists
    //   [12582912, 25165824)     mhist : 768 private 4096-bin u32 hists
    //   [25165824, 50331648)     res16 : 12.58M ushort (f16 residual / inf sentinel)
    //   [50331648, +192)         med   : 48 f32
    //   [50331904, +92)          s1d   : 23 f32
    //   [50332160, +384)         lohi  : 96 f32
    unsigned int*   phist = (unsigned int*)ws;
    unsigned int*   mhist = (unsigned int*)(ws + 12582912);
    unsigned short* res16 = (unsigned short*)(ws + 25165824);
    float* med  = (float*)(ws + 50331648);
    float* s1d  = (float*)(ws + 50331904);
    float* lohi = (float*)(ws + 50332160);

    k_hist  <<<768,  256, 0, stream>>>(x, mhist);
    k_medsel<<<48,   256, 0, stream>>>(mhist, kern, s1d, med);
    k_conv  <<<3072, 512, 0, stream>>>(x, mask, med, s1d, res16, phist);
    k_pct   <<<48,   256, 0, stream>>>(phist, lohi);
    k_final <<<6144, 256, 0, stream>>>(res16, lohi, out);
}